// Round 16
// baseline (625.010 us; speedup 1.0000x reference)
//
#include <hip/hip_runtime.h>
#include <math.h>

// Problem dims (fixed)
#define N_ 20000
#define E_ 100000
#define B_ 128
#define F_IN_ 14
#define DIM_ 64
#define E_FEAT_ 4
#define MLP_H_ 128
#define EWC_ 4096    // DIM*DIM
#define PC_ 8192     // MLP_H * DIM (P columns)
#define PC2_ 8256    // PC_ + 64 extra columns holding mlp_b2 (for Q via MFMA)

// setup_a block ranges
#define LIN0_BLKS 5000          // N_*64/256
#define DEG_BLKS 391            // ceil(E_/256)
#define PREPB_BLKS 2064         // ceil(PC2_*64/256)

typedef __attribute__((ext_vector_type(4))) float f32x4;
typedef __attribute__((ext_vector_type(8))) _Float16 halfx8;

// ---------------------------------------------------------------------------
// FUSED setup kernel A: lin0 | deg+batch_off | prep_b (validated r12/r14/r15).
__global__ __launch_bounds__(256) void setup_a(
        const float* __restrict__ x, const float* __restrict__ lw,
        const float* __restrict__ lb, float* __restrict__ out,
        const int* __restrict__ src, const int* __restrict__ dst,
        float* __restrict__ cnt, int* __restrict__ cnt_src,
        const int* __restrict__ batch, int* __restrict__ off_b,
        const float* __restrict__ w2, const float* __restrict__ b2,
        _Float16* __restrict__ Bf) {
    int b = blockIdx.x;
    int t = threadIdx.x;
    if (b < LIN0_BLKS) {
        int idx = b * 256 + t;
        int n = idx >> 6, d = idx & 63;
        float acc = lb[d];
#pragma unroll
        for (int f = 0; f < F_IN_; ++f) acc = fmaf(x[n * F_IN_ + f], lw[f * DIM_ + d], acc);
        out[idx] = acc > 0.f ? acc : 0.f;
    } else if (b < LIN0_BLKS + DEG_BLKS) {
        int e = (b - LIN0_BLKS) * 256 + t;
        if (e < E_) {
            atomicAdd(&cnt[dst[e]], 1.0f);
            atomicAdd(&cnt_src[src[e]], 1);
        }
        if (b == LIN0_BLKS && t <= B_) {
            int bb = t;
            int lo = 0, hi = N_;
            while (lo < hi) {
                int mid = (lo + hi) >> 1;
                if (batch[mid] < bb) lo = mid + 1; else hi = mid;
            }
            off_b[bb] = lo;
        }
    } else {
        int idx = (b - LIN0_BLKS - DEG_BLKS) * 256 + t;
        if (idx >= PC2_ * 64) return;
        int c16 = idx >> 10;
        int r   = idx & 1023;
        int ks  = r >> 9;
        int q   = (r >> 7) & 3;
        int lr  = (r >> 3) & 15;
        int j   = r & 7;
        int c = c16 * 16 + lr;
        int i = ks * 32 + q * 8 + j;
        float v;
        if (c < PC_) {
            int o = c >> 7, k = c & 127;
            v = w2[(size_t)k * EWC_ + i * 64 + o];
        } else {
            int o = c - PC_;
            v = b2[i * 64 + o];
        }
        Bf[idx] = (_Float16)v;
    }
}

// exclusive scan over N_ bins -> src_off[0..N_]
__global__ void scan_src(const int* __restrict__ cnt_src, int* __restrict__ src_off) {
    __shared__ int part[256];
    __shared__ int off[257];
    int t = threadIdx.x;
    const int per = (N_ + 255) / 256;
    int base = t * per;
    int s = 0;
    for (int i = 0; i < per; ++i) { int b = base + i; if (b < N_) s += cnt_src[b]; }
    part[t] = s;
    __syncthreads();
    if (t == 0) {
        int a = 0;
        for (int i = 0; i < 256; ++i) { off[i] = a; a += part[i]; }
        off[256] = a;
    }
    __syncthreads();
    int run = off[t];
    for (int i = 0; i < per; ++i) {
        int b = base + i;
        if (b < N_) { src_off[b] = run; run += cnt_src[b]; }
    }
    if (t == 0) src_off[N_] = off[256];
}

// FUSED scatter + edge-MLP layer 1 (validated r11..r15).
__global__ __launch_bounds__(256) void scatter_mlp1(
        const int* __restrict__ src, const int* __restrict__ dst,
        int* __restrict__ cur, const int* __restrict__ src_off,
        const float* __restrict__ ea, const float* __restrict__ w1,
        const float* __restrict__ b1, int* __restrict__ dsts,
        _Float16* __restrict__ h1s) {
    __shared__ float w1s[E_FEAT_ * MLP_H_];   // 2 KB
    __shared__ float b1s[MLP_H_];
    int t = threadIdx.x;
    if (t < MLP_H_) b1s[t] = b1[t];
    for (int i = t; i < E_FEAT_ * MLP_H_; i += 256) w1s[i] = w1[i];
    __syncthreads();
    int e = blockIdx.x * 256 + t;
    if (e >= E_) return;
    int s = src[e];
    int p = src_off[s] + atomicAdd(&cur[s], 1);
    dsts[p] = dst[e];
    float a0 = ea[e * 4 + 0], a1 = ea[e * 4 + 1];
    float a2 = ea[e * 4 + 2], a3 = ea[e * 4 + 3];
    _Float16* hrow = h1s + (size_t)p * 128;
#pragma unroll
    for (int k8 = 0; k8 < 16; ++k8) {
        halfx8 v;
#pragma unroll
        for (int j = 0; j < 8; ++j) {
            int k = k8 * 8 + j;
            float acc = b1s[k];
            acc = fmaf(a0, w1s[k], acc);
            acc = fmaf(a1, w1s[128 + k], acc);
            acc = fmaf(a2, w1s[256 + k], acc);
            acc = fmaf(a3, w1s[384 + k], acc);
            v[j] = (_Float16)(acc > 0.f ? acc : 0.f);
        }
        *(halfx8*)&hrow[k8 * 8] = v;
    }
}

// ---------------------------------------------------------------------------
// FUSED message kernel (v11): 32 nodes/block, o-chunk 16, 128 KB LDS.
// Halves the Bf L2 stream (625 blocks x 1 MB vs r8's 1250 x 1 MB) while
// keeping r8's edge structure EXACTLY (full o-16, no duplicate MFMAs, no
// h1s re-reads — the r9 defects). Cost: 1 block/CU. Single controlled var.
// LDS: addr = o*4096 + node*128 + (k ^ ((node>>2 & 3)<<5) ^ ((o&7)<<3)).
__global__ __launch_bounds__(512, 2) void fused_msg(
        const float* __restrict__ out, const _Float16* __restrict__ Bf,
        const _Float16* __restrict__ h1s,
        const int* __restrict__ dsts, const int* __restrict__ src_off,
        float* __restrict__ agg) {
    __shared__ _Float16 Plds[16 * 4096];   // 128 KB
    const int tid = threadIdx.x;
    const int lane = tid & 63;
    const int w = __builtin_amdgcn_readfirstlane(tid >> 6);   // 0..7
    const int lrow = lane & 15, quad = lane >> 4;
    const int nb0 = blockIdx.x * 32;

    // A fragments for 32 nodes: group A = nodes 0-15, group B = 16-31.
    halfx8 aA[2], aB[2];
    {
        const float* orowA = out + (size_t)(nb0 + lrow) * 64 + quad * 8;
        const float* orowB = out + (size_t)(nb0 + 16 + lrow) * 64 + quad * 8;
#pragma unroll
        for (int ks = 0; ks < 2; ++ks) {
            float4 v0 = *(const float4*)(orowA + ks * 32);
            float4 v1 = *(const float4*)(orowA + ks * 32 + 4);
            aA[ks][0] = (_Float16)v0.x; aA[ks][1] = (_Float16)v0.y;
            aA[ks][2] = (_Float16)v0.z; aA[ks][3] = (_Float16)v0.w;
            aA[ks][4] = (_Float16)v1.x; aA[ks][5] = (_Float16)v1.y;
            aA[ks][6] = (_Float16)v1.z; aA[ks][7] = (_Float16)v1.w;
            float4 u0 = *(const float4*)(orowB + ks * 32);
            float4 u1 = *(const float4*)(orowB + ks * 32 + 4);
            aB[ks][0] = (_Float16)u0.x; aB[ks][1] = (_Float16)u0.y;
            aB[ks][2] = (_Float16)u0.z; aB[ks][3] = (_Float16)u0.w;
            aB[ks][4] = (_Float16)u1.x; aB[ks][5] = (_Float16)u1.y;
            aB[ks][6] = (_Float16)u1.z; aB[ks][7] = (_Float16)u1.w;
        }
    }

    // Q via MFMA, both groups: qfX[f][r] = Q[group node quad*4+r][f*16+lrow]
    f32x4 qfA[4], qfB[4];
#pragma unroll
    for (int f = 0; f < 4; ++f) {
        const _Float16* bc = &Bf[(size_t)(512 + f) * 1024 + quad * 128 + lrow * 8];
        halfx8 bq0 = *(const halfx8*)bc;
        halfx8 bq1 = *(const halfx8*)(bc + 512);
        f32x4 z = (f32x4){0.f, 0.f, 0.f, 0.f};
        z = __builtin_amdgcn_mfma_f32_16x16x32_f16(aA[0], bq0, z, 0, 0, 0);
        z = __builtin_amdgcn_mfma_f32_16x16x32_f16(aA[1], bq1, z, 0, 0, 0);
        qfA[f] = z;
        f32x4 z2 = (f32x4){0.f, 0.f, 0.f, 0.f};
        z2 = __builtin_amdgcn_mfma_f32_16x16x32_f16(aB[0], bq0, z2, 0, 0, 0);
        z2 = __builtin_amdgcn_mfma_f32_16x16x32_f16(aB[1], bq1, z2, 0, 0, 0);
        qfB[f] = z2;
    }

    // Wave owns nodes {2w, 2w+1} (A) and {16+2w, 16+2w+1} (B).
    const int nA = nb0 + 2 * w;
    const int nB = nb0 + 16 + 2 * w;
    const int begA0 = src_off[nA], endA0 = src_off[nA + 1], endA1 = src_off[nA + 2];
    const int begB0 = src_off[nB], endB0 = src_off[nB + 1], endB1 = src_off[nB + 2];

#pragma unroll
    for (int p = 0; p < 4; ++p) {
        if (p) __syncthreads();   // edge phase of pass p-1 done before overwrite

        // ---- GEMM phase: pass p covers Bf tiles [p*128, p*128+128) ----
#pragma unroll 8
        for (int nf = 0; nf < 16; ++nf) {
            int cl = w * 256 + nf * 16 + lrow;          // pass-local col 0..2047
            size_t tb = (size_t)(p * 128 + w * 16 + nf) * 1024 + quad * 128 + lrow * 8;
            halfx8 b0 = *(const halfx8*)&Bf[tb];
            halfx8 b1 = *(const halfx8*)&Bf[tb + 512];
            f32x4 accA = (f32x4){0.f, 0.f, 0.f, 0.f};
            f32x4 accB = (f32x4){0.f, 0.f, 0.f, 0.f};
            accA = __builtin_amdgcn_mfma_f32_16x16x32_f16(aA[0], b0, accA, 0, 0, 0);
            accA = __builtin_amdgcn_mfma_f32_16x16x32_f16(aA[1], b1, accA, 0, 0, 0);
            accB = __builtin_amdgcn_mfma_f32_16x16x32_f16(aB[0], b0, accB, 0, 0, 0);
            accB = __builtin_amdgcn_mfma_f32_16x16x32_f16(aB[1], b1, accB, 0, 0, 0);
            // C-frags: col = lrow, rows = node quad*4+rr (group B +16).
            int o = cl >> 7, k = cl & 127;              // o_loc 0..15
            int kz = k ^ (quad << 5) ^ ((o & 7) << 3);  // (node>>2)&3 == quad
            int base = o * 4096 + kz;
#pragma unroll
            for (int rr = 0; rr < 4; ++rr) {
                Plds[base + (quad * 4 + rr) * 128] = (_Float16)accA[rr];
                Plds[base + (16 + quad * 4 + rr) * 128] = (_Float16)accB[rr];
            }
        }
        __syncthreads();

        // ---- edge phase for o-chunk [o0, o0+16) — r8 structure, 4 nodes ----
        int o0 = p * 16;
#pragma unroll
        for (int nn = 0; nn < 4; ++nn) {
            int nl15 = 2 * w + (nn & 1);
            int nl = ((nn >> 1) << 4) | nl15;       // node local 0..31
            int beg  = (nn == 0) ? begA0 : (nn == 1) ? endA0
                     : (nn == 2) ? begB0 : endB0;
            int endv = (nn == 0) ? endA0 : (nn == 1) ? endA1
                     : (nn == 2) ? endB0 : endB1;
            if (beg == endv) continue;
            // qv = Q[node][o0+lrow], from holding lane of qfA/qfB[p]
            f32x4 qq = (nn >> 1) ? qfB[p] : qfA[p];     // static idx (unrolled)
            int rsel = nl15 & 3;
            float qel = rsel == 0 ? qq[0] : rsel == 1 ? qq[1]
                      : rsel == 2 ? qq[2] : qq[3];
            int srcl = ((nl15 >> 2) << 4) | lrow;
            float qv = __shfl(qel, srcl, 64);
            // B-frag: col = lrow (o), k = ks*32 + quad*8 + j, swizzled LDS
            halfx8 bf[4];
#pragma unroll
            for (int ks = 0; ks < 4; ++ks) {
                int kk = (ks * 32 + quad * 8) ^ (((nl >> 2) & 3) << 5)
                       ^ ((lrow & 7) << 3);
                bf[ks] = *(const halfx8*)&Plds[lrow * 4096 + nl * 128 + kk];
            }
            for (int g = beg; g < endv; g += 16) {
                int gcnt = endv - g; if (gcnt > 16) gcnt = 16;
                int ei = lrow < gcnt ? lrow : gcnt - 1;
                int gi = g + ei;                 // affine, no indirection
                int dv = dsts[gi];
                halfx8 af[4];
#pragma unroll
                for (int ks = 0; ks < 4; ++ks)
                    af[ks] = *(const halfx8*)&h1s[(size_t)gi * 128 + ks * 32 + quad * 8];
                f32x4 acc = (f32x4){0.f, 0.f, 0.f, 0.f};
#pragma unroll
                for (int ks = 0; ks < 4; ++ks)
                    acc = __builtin_amdgcn_mfma_f32_16x16x32_f16(
                        af[ks], bf[ks], acc, 0, 0, 0);
                // C-frag: col = lrow (o), rows = quad*4+rr (edges)
#pragma unroll
                for (int rr = 0; rr < 4; ++rr) {
                    int j = quad * 4 + rr;
                    int d = __shfl(dv, j, 64);
                    if (j < gcnt) {
                        atomicAdd(&agg[(size_t)d * 64 + o0 + lrow], acc[rr] + qv);
                    }
                }
            }
        }
    }
}

// ---------------------------------------------------------------------------
// GRU — exact r11 version (32 nodes/block, 256 threads; validated in the
// 583/576 µs runs). Resets agg after consuming.
__global__ __launch_bounds__(256) void gru_kernel(float* __restrict__ out,
                                                  float* __restrict__ agg,
                                                  const float* __restrict__ cnt,
                                                  const float* __restrict__ root,
                                                  const float* __restrict__ cbias,
                                                  const float* __restrict__ wi,
                                                  const float* __restrict__ wh,
                                                  const float* __restrict__ bi,
                                                  const float* __restrict__ bh) {
    __shared__ float root_s[64 * 64];
    __shared__ float h_s[32 * 64];
    __shared__ float m_s[32 * 64];
    int tid = threadIdx.x;
    int lane = tid & 63;
    int wv = __builtin_amdgcn_readfirstlane(tid >> 6);
    int nb = blockIdx.x * 32;
#pragma unroll
    for (int it = 0; it < 4; ++it) {
        int i = it * 1024 + tid * 4;
        *(float4*)&root_s[i] = *(const float4*)&root[i];
    }
#pragma unroll
    for (int it = 0; it < 2; ++it) {
        int i = it * 1024 + tid * 4;
        *(float4*)&h_s[i] = *(const float4*)&out[(size_t)nb * 64 + i];
    }
    __syncthreads();

    int nbase = nb + wv * 8;
    float a[8];
#pragma unroll
    for (int j = 0; j < 8; ++j) {
        int n = nbase + j;
        float c = cnt[n]; c = c > 1.f ? c : 1.f;
        a[j] = agg[(size_t)n * 64 + lane] / c + cbias[lane];
        agg[(size_t)n * 64 + lane] = 0.f;   // re-zero for next step
    }
    for (int i = 0; i < 64; ++i) {
        float rv = root_s[i * 64 + lane];
#pragma unroll
        for (int j = 0; j < 8; ++j)
            a[j] = fmaf(h_s[(wv * 8 + j) * 64 + i], rv, a[j]);
    }
#pragma unroll
    for (int j = 0; j < 8; ++j) {
        float m = a[j] > 0.f ? a[j] : 0.f;
        m_s[(wv * 8 + j) * 64 + lane] = m;
    }
    __syncthreads();

    float gir[8], giz[8], gin[8], ghr[8], ghz[8], ghn[8];
    float bi0 = bi[lane], bi1 = bi[64 + lane], bi2 = bi[128 + lane];
    float bh0 = bh[lane], bh1 = bh[64 + lane], bh2 = bh[128 + lane];
#pragma unroll
    for (int j = 0; j < 8; ++j) {
        gir[j] = bi0; giz[j] = bi1; gin[j] = bi2;
        ghr[j] = bh0; ghz[j] = bh1; ghn[j] = bh2;
    }
    for (int i = 0; i < 64; ++i) {
        float w0 = wi[i * 192 + lane];
        float w1 = wi[i * 192 + 64 + lane];
        float w2v = wi[i * 192 + 128 + lane];
        float u0 = wh[i * 192 + lane];
        float u1 = wh[i * 192 + 64 + lane];
        float u2 = wh[i * 192 + 128 + lane];
#pragma unroll
        for (int j = 0; j < 8; ++j) {
            float mi = m_s[(wv * 8 + j) * 64 + i];
            float hi = h_s[(wv * 8 + j) * 64 + i];
            gir[j] = fmaf(mi, w0, gir[j]);
            giz[j] = fmaf(mi, w1, giz[j]);
            gin[j] = fmaf(mi, w2v, gin[j]);
            ghr[j] = fmaf(hi, u0, ghr[j]);
            ghz[j] = fmaf(hi, u1, ghz[j]);
            ghn[j] = fmaf(hi, u2, ghn[j]);
        }
    }
#pragma unroll
    for (int j = 0; j < 8; ++j) {
        int n = nbase + j;
        float rg = 1.f / (1.f + expf(-(gir[j] + ghr[j])));
        float zg = 1.f / (1.f + expf(-(giz[j] + ghz[j])));
        float ng = tanhf(gin[j] + rg * ghn[j]);
        float h = h_s[(wv * 8 + j) * 64 + lane];
        out[(size_t)n * 64 + lane] = (1.f - zg) * ng + zg * h;
    }
}

// ---------------------------------------------------------------------------
// Fully fused Set2Set: ALL 3 steps in one kernel (r11, validated).
__global__ __launch_bounds__(256) void lstm_all_kernel(
        const float* __restrict__ out, const int* __restrict__ off_b,
        float* __restrict__ e_ws,
        const float* __restrict__ wi, const float* __restrict__ wh,
        const float* __restrict__ bi, const float* __restrict__ bh,
        const float* __restrict__ hw1, const float* __restrict__ hb1,
        const float* __restrict__ hw2, const float* __restrict__ hb2,
        float* __restrict__ y) {
    int b = blockIdx.x;
    int t = threadIdx.x;
    __shared__ float qs[128], hs[64], cs[64], g[256];
    __shared__ float q[64];
    __shared__ float red[256], racc[256], sasum[4];

    if (t < 128) qs[t] = 0.f;
    if (t < 64) { hs[t] = 0.f; cs[t] = 0.f; }
    __syncthreads();

    int start = off_b[b], end = off_b[b + 1];

    for (int s = 0; s < 3; ++s) {
        // ---- LSTM cell ----
        {
            float acc = bi[t] + bh[t];
#pragma unroll 8
            for (int i = 0; i < 128; ++i) acc = fmaf(qs[i], wi[i * 256 + t], acc);
#pragma unroll 8
            for (int i = 0; i < 64; ++i) acc = fmaf(hs[i], wh[i * 256 + t], acc);
            g[t] = acc;
        }
        __syncthreads();
        if (t < 64) {
            float ig = 1.f / (1.f + expf(-g[t]));
            float fg = 1.f / (1.f + expf(-g[64 + t]));
            float gg = tanhf(g[128 + t]);
            float og = 1.f / (1.f + expf(-g[192 + t]));
            float c = fg * cs[t] + ig * gg;
            cs[t] = c;
            float h = og * tanhf(c);
            hs[t] = h;
            q[t] = h;
        }
        __syncthreads();

        // ---- attention ----
        float lmax = -1e30f;
        for (int n = start + t; n < end; n += 256) {
            float acc = 0.f;
#pragma unroll 16
            for (int d2 = 0; d2 < 64; ++d2) acc = fmaf(out[n * 64 + d2], q[d2], acc);
            e_ws[n] = acc;
            lmax = fmaxf(lmax, acc);
        }
        red[t] = lmax;
        __syncthreads();
        for (int s2 = 128; s2 > 0; s2 >>= 1) {
            if (t < s2) red[t] = fmaxf(red[t], red[t + s2]);
            __syncthreads();
        }
        float emax = red[0];
        int w = t >> 6, d = t & 63;
        float rl = 0.f, lasum = 0.f;
        for (int n = start + w; n < end; n += 4) {
            float a = expf(e_ws[n] - emax);
            rl = fmaf(a, out[n * 64 + d], rl);
            if (d == 0) lasum += a;
        }
        racc[t] = rl;
        if (d == 0) sasum[w] = lasum;
        __syncthreads();
        if (t < 64) {
            float r = racc[t] + racc[64 + t] + racc[128 + t] + racc[192 + t];
            float as = sasum[0] + sasum[1] + sasum[2] + sasum[3];
            as = fmaxf(as, 1e-16f);
            qs[t] = q[t];
            qs[64 + t] = r / as;
        }
        __syncthreads();
    }

    // ---- output head ----
    if (t < 64) {
        float acc = hb1[t];
#pragma unroll 8
        for (int i = 0; i < 128; ++i) acc = fmaf(qs[i], hw1[i * 64 + t], acc);
        acc = acc > 0.f ? acc : 0.f;
        float p = acc * hw2[t];
        for (int off = 32; off > 0; off >>= 1) p += __shfl_down(p, off, 64);
        if (t == 0) y[b] = p + hb2[0];
    }
}

extern "C" void kernel_launch(void* const* d_in, const int* in_sizes, int n_in,
                              void* d_out, int out_size, void* d_ws, size_t ws_size,
                              hipStream_t stream) {
    (void)in_sizes; (void)n_in; (void)out_size; (void)ws_size;
    const float* x        = (const float*)d_in[0];
    const float* ea       = (const float*)d_in[1];
    const int*   eidx     = (const int*)d_in[2];
    const int*   batch    = (const int*)d_in[3];
    const float* lin0_w   = (const float*)d_in[4];
    const float* lin0_b   = (const float*)d_in[5];
    const float* mlp_w1   = (const float*)d_in[6];
    const float* mlp_b1   = (const float*)d_in[7];
    const float* mlp_w2   = (const float*)d_in[8];
    const float* mlp_b2   = (const float*)d_in[9];
    const float* conv_root= (const float*)d_in[10];
    const float* conv_bias= (const float*)d_in[11];
    const float* gru_wi   = (const float*)d_in[12];
    const float* gru_wh   = (const float*)d_in[13];
    const float* gru_bi   = (const float*)d_in[14];
    const float* gru_bh   = (const float*)d_in[15];
    const float* lstm_wi  = (const float*)d_in[16];
    const float* lstm_wh  = (const float*)d_in[17];
    const float* lstm_bi  = (const float*)d_in[18];
    const float* lstm_bh  = (const float*)d_in[19];
    const float* lin1_w   = (const float*)d_in[20];
    const float* lin1_b   = (const float*)d_in[21];
    const float* lin2_w   = (const float*)d_in[22];
    const float* lin2_b   = (const float*)d_in[23];
    float* y = (float*)d_out;

    const int* src = eidx;
    const int* dst = eidx + E_;

    char* w = (char*)d_ws;
    auto carve = [&](size_t bytes) {
        char* p = w;
        w += (bytes + 255) & ~(size_t)255;
        return p;
    };
    float* out_buf = (float*)carve((size_t)N_ * DIM_ * 4);
    float* e_ws    = (float*)carve((size_t)N_ * 4);
    int*   off_b   = (int*)carve((size_t)(B_ + 1) * 4);
    _Float16* h1s  = (_Float16*)carve((size_t)E_ * MLP_H_ * 2);
    _Float16* Bf   = (_Float16*)carve((size_t)PC2_ * 64 * 2);
    int*   src_off = (int*)carve((size_t)(N_ + 1) * 4);
    int*   dsts    = (int*)carve((size_t)E_ * 4);
    // contiguous zero zone (single memset)
    char*  zero0   = w;
    float* agg     = (float*)carve((size_t)N_ * DIM_ * 4);
    float* cnt     = (float*)carve((size_t)N_ * 4);
    int*   cnt_src = (int*)carve((size_t)N_ * 4);
    int*   cur     = (int*)carve((size_t)N_ * 4);
    size_t zbytes  = (size_t)(w - zero0);

    hipMemsetAsync(zero0, 0, zbytes, stream);

    setup_a<<<LIN0_BLKS + DEG_BLKS + PREPB_BLKS, 256, 0, stream>>>(
        x, lin0_w, lin0_b, out_buf, src, dst, cnt, cnt_src, batch, off_b,
        mlp_w2, mlp_b2, Bf);
    scan_src<<<1, 256, 0, stream>>>(cnt_src, src_off);
    scatter_mlp1<<<(E_ + 255) / 256, 256, 0, stream>>>(src, dst, cur, src_off,
                                                       ea, mlp_w1, mlp_b1,
                                                       dsts, h1s);

    for (int step = 0; step < 3; ++step) {
        fused_msg<<<N_ / 32, 512, 0, stream>>>(out_buf, Bf, h1s, dsts,
                                               src_off, agg);
        gru_kernel<<<N_ / 32, 256, 0, stream>>>(out_buf, agg, cnt, conv_root,
                                                conv_bias, gru_wi, gru_wh,
                                                gru_bi, gru_bh);
    }

    lstm_all_kernel<<<B_, 256, 0, stream>>>(out_buf, off_b, e_ws,
                                            lstm_wi, lstm_wh, lstm_bi, lstm_bh,
                                            lin1_w, lin1_b, lin2_w, lin2_b, y);
}

// Round 17
// 573.777 us; speedup vs baseline: 1.0893x; 1.0893x over previous
//
#include <hip/hip_runtime.h>
#include <math.h>

// Problem dims (fixed)
#define N_ 20000
#define E_ 100000
#define B_ 128
#define F_IN_ 14
#define DIM_ 64
#define E_FEAT_ 4
#define MLP_H_ 128
#define EWC_ 4096    // DIM*DIM
#define PC_ 8192     // MLP_H * DIM (P columns)
#define PC2_ 8256    // PC_ + 64 extra columns holding mlp_b2 (for Q via MFMA)

// setup_a block ranges
#define LIN0_BLKS 5000          // N_*64/256
#define DEG_BLKS 391            // ceil(E_/256)
#define PREPB_BLKS 2064         // ceil(PC2_*64/256)

typedef __attribute__((ext_vector_type(4))) float f32x4;
typedef __attribute__((ext_vector_type(8))) _Float16 halfx8;

// ---------------------------------------------------------------------------
// FUSED setup kernel A: lin0 | deg+batch_off | prep_b (validated r12/r14/r15).
__global__ __launch_bounds__(256) void setup_a(
        const float* __restrict__ x, const float* __restrict__ lw,
        const float* __restrict__ lb, float* __restrict__ out,
        const int* __restrict__ src, const int* __restrict__ dst,
        float* __restrict__ cnt, int* __restrict__ cnt_src,
        const int* __restrict__ batch, int* __restrict__ off_b,
        const float* __restrict__ w2, const float* __restrict__ b2,
        _Float16* __restrict__ Bf) {
    int b = blockIdx.x;
    int t = threadIdx.x;
    if (b < LIN0_BLKS) {
        int idx = b * 256 + t;
        int n = idx >> 6, d = idx & 63;
        float acc = lb[d];
#pragma unroll
        for (int f = 0; f < F_IN_; ++f) acc = fmaf(x[n * F_IN_ + f], lw[f * DIM_ + d], acc);
        out[idx] = acc > 0.f ? acc : 0.f;
    } else if (b < LIN0_BLKS + DEG_BLKS) {
        int e = (b - LIN0_BLKS) * 256 + t;
        if (e < E_) {
            atomicAdd(&cnt[dst[e]], 1.0f);
            atomicAdd(&cnt_src[src[e]], 1);
        }
        if (b == LIN0_BLKS && t <= B_) {
            int bb = t;
            int lo = 0, hi = N_;
            while (lo < hi) {
                int mid = (lo + hi) >> 1;
                if (batch[mid] < bb) lo = mid + 1; else hi = mid;
            }
            off_b[bb] = lo;
        }
    } else {
        int idx = (b - LIN0_BLKS - DEG_BLKS) * 256 + t;
        if (idx >= PC2_ * 64) return;
        int c16 = idx >> 10;
        int r   = idx & 1023;
        int ks  = r >> 9;
        int q   = (r >> 7) & 3;
        int lr  = (r >> 3) & 15;
        int j   = r & 7;
        int c = c16 * 16 + lr;
        int i = ks * 32 + q * 8 + j;
        float v;
        if (c < PC_) {
            int o = c >> 7, k = c & 127;
            v = w2[(size_t)k * EWC_ + i * 64 + o];
        } else {
            int o = c - PC_;
            v = b2[i * 64 + o];
        }
        Bf[idx] = (_Float16)v;
    }
}

// exclusive scan over N_ bins -> src_off[0..N_]
__global__ void scan_src(const int* __restrict__ cnt_src, int* __restrict__ src_off) {
    __shared__ int part[256];
    __shared__ int off[257];
    int t = threadIdx.x;
    const int per = (N_ + 255) / 256;
    int base = t * per;
    int s = 0;
    for (int i = 0; i < per; ++i) { int b = base + i; if (b < N_) s += cnt_src[b]; }
    part[t] = s;
    __syncthreads();
    if (t == 0) {
        int a = 0;
        for (int i = 0; i < 256; ++i) { off[i] = a; a += part[i]; }
        off[256] = a;
    }
    __syncthreads();
    int run = off[t];
    for (int i = 0; i < per; ++i) {
        int b = base + i;
        if (b < N_) { src_off[b] = run; run += cnt_src[b]; }
    }
    if (t == 0) src_off[N_] = off[256];
}

// FUSED scatter + edge-MLP layer 1 (validated r11..r15).
__global__ __launch_bounds__(256) void scatter_mlp1(
        const int* __restrict__ src, const int* __restrict__ dst,
        int* __restrict__ cur, const int* __restrict__ src_off,
        const float* __restrict__ ea, const float* __restrict__ w1,
        const float* __restrict__ b1, int* __restrict__ dsts,
        _Float16* __restrict__ h1s) {
    __shared__ float w1s[E_FEAT_ * MLP_H_];   // 2 KB
    __shared__ float b1s[MLP_H_];
    int t = threadIdx.x;
    if (t < MLP_H_) b1s[t] = b1[t];
    for (int i = t; i < E_FEAT_ * MLP_H_; i += 256) w1s[i] = w1[i];
    __syncthreads();
    int e = blockIdx.x * 256 + t;
    if (e >= E_) return;
    int s = src[e];
    int p = src_off[s] + atomicAdd(&cur[s], 1);
    dsts[p] = dst[e];
    float a0 = ea[e * 4 + 0], a1 = ea[e * 4 + 1];
    float a2 = ea[e * 4 + 2], a3 = ea[e * 4 + 3];
    _Float16* hrow = h1s + (size_t)p * 128;
#pragma unroll
    for (int k8 = 0; k8 < 16; ++k8) {
        halfx8 v;
#pragma unroll
        for (int j = 0; j < 8; ++j) {
            int k = k8 * 8 + j;
            float acc = b1s[k];
            acc = fmaf(a0, w1s[k], acc);
            acc = fmaf(a1, w1s[128 + k], acc);
            acc = fmaf(a2, w1s[256 + k], acc);
            acc = fmaf(a3, w1s[384 + k], acc);
            v[j] = (_Float16)(acc > 0.f ? acc : 0.f);
        }
        *(halfx8*)&hrow[k8 * 8] = v;
    }
}

// ---------------------------------------------------------------------------
// FUSED message kernel — exact r8 (the 92 µs configuration). UNCHANGED.
// 16 nodes/block, 512 threads, 4 o-passes of 16, coalesced tiled Bf stream.
// LDS swizzle: addr = o*2048 + node*128 + (k ^ ((node>>2)<<5) ^ ((o&7)<<3)).
__global__ __launch_bounds__(512, 4) void fused_msg(
        const float* __restrict__ out, const _Float16* __restrict__ Bf,
        const _Float16* __restrict__ h1s,
        const int* __restrict__ dsts, const int* __restrict__ src_off,
        float* __restrict__ agg) {
    __shared__ _Float16 Plds[16 * 2048];   // 64 KB
    const int tid = threadIdx.x;
    const int lane = tid & 63;
    const int w = __builtin_amdgcn_readfirstlane(tid >> 6);   // 0..7
    const int lrow = lane & 15, quad = lane >> 4;
    const int nb0 = blockIdx.x * 16;

    // GEMM A fragments (16 nodes x K=64), loaded once, reused all 4 passes.
    halfx8 aG[2];
    {
        const float* orow = out + (size_t)(nb0 + lrow) * 64 + quad * 8;
#pragma unroll
        for (int ks = 0; ks < 2; ++ks) {
            float4 v0 = *(const float4*)(orow + ks * 32);
            float4 v1 = *(const float4*)(orow + ks * 32 + 4);
            aG[ks][0] = (_Float16)v0.x; aG[ks][1] = (_Float16)v0.y;
            aG[ks][2] = (_Float16)v0.z; aG[ks][3] = (_Float16)v0.w;
            aG[ks][4] = (_Float16)v1.x; aG[ks][5] = (_Float16)v1.y;
            aG[ks][6] = (_Float16)v1.z; aG[ks][7] = (_Float16)v1.w;
        }
    }

    // Q via MFMA: qf[f][r] = Q[node = quad*4+r][o = f*16 + lrow]
    f32x4 qf[4];
#pragma unroll
    for (int f = 0; f < 4; ++f) {
        const _Float16* bc = &Bf[(size_t)(512 + f) * 1024 + quad * 128 + lrow * 8];
        halfx8 bq0 = *(const halfx8*)bc;
        halfx8 bq1 = *(const halfx8*)(bc + 512);
        f32x4 z = (f32x4){0.f, 0.f, 0.f, 0.f};
        z = __builtin_amdgcn_mfma_f32_16x16x32_f16(aG[0], bq0, z, 0, 0, 0);
        z = __builtin_amdgcn_mfma_f32_16x16x32_f16(aG[1], bq1, z, 0, 0, 0);
        qf[f] = z;
    }

    // Hoisted per-wave node bookkeeping (wave owns nodes 2w, 2w+1).
    const int n0g = nb0 + 2 * w;
    const int beg0 = src_off[n0g];
    const int end0 = src_off[n0g + 1];
    const int end1 = src_off[n0g + 2];

#pragma unroll
    for (int p = 0; p < 4; ++p) {
        if (p) __syncthreads();   // edge phase of pass p-1 done before overwrite

        // ---- GEMM phase: this wave covers 256 of the pass's 2048 columns ----
#pragma unroll 8
        for (int nf = 0; nf < 16; ++nf) {
            int cl = w * 256 + nf * 16 + lrow;          // pass-local col 0..2047
            size_t tb = (size_t)(p * 128 + w * 16 + nf) * 1024 + quad * 128 + lrow * 8;
            halfx8 b0 = *(const halfx8*)&Bf[tb];
            halfx8 b1 = *(const halfx8*)&Bf[tb + 512];
            f32x4 acc = (f32x4){0.f, 0.f, 0.f, 0.f};
            acc = __builtin_amdgcn_mfma_f32_16x16x32_f16(aG[0], b0, acc, 0, 0, 0);
            acc = __builtin_amdgcn_mfma_f32_16x16x32_f16(aG[1], b1, acc, 0, 0, 0);
            // C-frag: col = lrow (this c), rows = quad*4+rr (nodes). o uniform.
            int o = cl >> 7, k = cl & 127;
            int kz = k ^ (quad << 5) ^ ((o & 7) << 3);  // node>>2 == quad here
            int base = o * 2048 + kz;
#pragma unroll
            for (int rr = 0; rr < 4; ++rr)
                Plds[base + (quad * 4 + rr) * 128] = (_Float16)acc[rr];
        }
        __syncthreads();

        // ---- edge phase for o-chunk [o0, o0+16) ----
        int o0 = p * 16;
#pragma unroll
        for (int nn = 0; nn < 2; ++nn) {
            int nl = 2 * w + nn;                 // node local 0..15
            int beg = nn ? end0 : beg0;
            int endv = nn ? end1 : end0;
            if (beg == endv) continue;
            // qv = Q[nb0+nl][o0+lrow], fetched from the holding lane of qf[p]
            int srcl = ((nl >> 2) << 4) | lrow;
            int rsel = nl & 3;
            float qel = rsel == 0 ? qf[p][0] : rsel == 1 ? qf[p][1]
                      : rsel == 2 ? qf[p][2] : qf[p][3];
            float qv = __shfl(qel, srcl, 64);
            // B-frag: col = lrow (o), k = ks*32 + quad*8 + j, from swizzled LDS
            halfx8 bf[4];
#pragma unroll
            for (int ks = 0; ks < 4; ++ks) {
                int kk = (ks * 32 + quad * 8) ^ ((nl >> 2) << 5) ^ ((lrow & 7) << 3);
                bf[ks] = *(const halfx8*)&Plds[lrow * 2048 + nl * 128 + kk];
            }
            for (int g = beg; g < endv; g += 16) {
                int gcnt = endv - g; if (gcnt > 16) gcnt = 16;
                int ei = lrow < gcnt ? lrow : gcnt - 1;
                int gi = g + ei;                 // affine, no indirection
                int dv = dsts[gi];
                halfx8 af[4];
#pragma unroll
                for (int ks = 0; ks < 4; ++ks)
                    af[ks] = *(const halfx8*)&h1s[(size_t)gi * 128 + ks * 32 + quad * 8];
                f32x4 acc = (f32x4){0.f, 0.f, 0.f, 0.f};
#pragma unroll
                for (int ks = 0; ks < 4; ++ks)
                    acc = __builtin_amdgcn_mfma_f32_16x16x32_f16(
                        af[ks], bf[ks], acc, 0, 0, 0);
                // C-frag: col = lrow (o), rows = quad*4+rr (edges)
#pragma unroll
                for (int rr = 0; rr < 4; ++rr) {
                    int j = quad * 4 + rr;
                    int d = __shfl(dv, j, 64);
                    if (j < gcnt) {
                        atomicAdd(&agg[(size_t)d * 64 + o0 + lrow], acc[rr] + qv);
                    }
                }
            }
        }
    }
}

// ---------------------------------------------------------------------------
// GRU — exact r11 version (32 nodes/block, 256 threads, 8 nodes/wave; the
// configuration measured in the 583/576 µs runs). Resets agg after consuming.
__global__ __launch_bounds__(256) void gru_kernel(float* __restrict__ out,
                                                  float* __restrict__ agg,
                                                  const float* __restrict__ cnt,
                                                  const float* __restrict__ root,
                                                  const float* __restrict__ cbias,
                                                  const float* __restrict__ wi,
                                                  const float* __restrict__ wh,
                                                  const float* __restrict__ bi,
                                                  const float* __restrict__ bh) {
    __shared__ float root_s[64 * 64];
    __shared__ float h_s[32 * 64];
    __shared__ float m_s[32 * 64];
    int tid = threadIdx.x;
    int lane = tid & 63;
    int wv = __builtin_amdgcn_readfirstlane(tid >> 6);
    int nb = blockIdx.x * 32;
#pragma unroll
    for (int it = 0; it < 4; ++it) {
        int i = it * 1024 + tid * 4;
        *(float4*)&root_s[i] = *(const float4*)&root[i];
    }
#pragma unroll
    for (int it = 0; it < 2; ++it) {
        int i = it * 1024 + tid * 4;
        *(float4*)&h_s[i] = *(const float4*)&out[(size_t)nb * 64 + i];
    }
    __syncthreads();

    int nbase = nb + wv * 8;
    float a[8];
#pragma unroll
    for (int j = 0; j < 8; ++j) {
        int n = nbase + j;
        float c = cnt[n]; c = c > 1.f ? c : 1.f;
        a[j] = agg[(size_t)n * 64 + lane] / c + cbias[lane];
        agg[(size_t)n * 64 + lane] = 0.f;   // re-zero for next step
    }
    for (int i = 0; i < 64; ++i) {
        float rv = root_s[i * 64 + lane];
#pragma unroll
        for (int j = 0; j < 8; ++j)
            a[j] = fmaf(h_s[(wv * 8 + j) * 64 + i], rv, a[j]);
    }
#pragma unroll
    for (int j = 0; j < 8; ++j) {
        float m = a[j] > 0.f ? a[j] : 0.f;
        m_s[(wv * 8 + j) * 64 + lane] = m;
    }
    __syncthreads();

    float gir[8], giz[8], gin[8], ghr[8], ghz[8], ghn[8];
    float bi0 = bi[lane], bi1 = bi[64 + lane], bi2 = bi[128 + lane];
    float bh0 = bh[lane], bh1 = bh[64 + lane], bh2 = bh[128 + lane];
#pragma unroll
    for (int j = 0; j < 8; ++j) {
        gir[j] = bi0; giz[j] = bi1; gin[j] = bi2;
        ghr[j] = bh0; ghz[j] = bh1; ghn[j] = bh2;
    }
    for (int i = 0; i < 64; ++i) {
        float w0 = wi[i * 192 + lane];
        float w1 = wi[i * 192 + 64 + lane];
        float w2v = wi[i * 192 + 128 + lane];
        float u0 = wh[i * 192 + lane];
        float u1 = wh[i * 192 + 64 + lane];
        float u2 = wh[i * 192 + 128 + lane];
#pragma unroll
        for (int j = 0; j < 8; ++j) {
            float mi = m_s[(wv * 8 + j) * 64 + i];
            float hi = h_s[(wv * 8 + j) * 64 + i];
            gir[j] = fmaf(mi, w0, gir[j]);
            giz[j] = fmaf(mi, w1, giz[j]);
            gin[j] = fmaf(mi, w2v, gin[j]);
            ghr[j] = fmaf(hi, u0, ghr[j]);
            ghz[j] = fmaf(hi, u1, ghz[j]);
            ghn[j] = fmaf(hi, u2, ghn[j]);
        }
    }
#pragma unroll
    for (int j = 0; j < 8; ++j) {
        int n = nbase + j;
        float rg = 1.f / (1.f + expf(-(gir[j] + ghr[j])));
        float zg = 1.f / (1.f + expf(-(giz[j] + ghz[j])));
        float ng = tanhf(gin[j] + rg * ghn[j]);
        float h = h_s[(wv * 8 + j) * 64 + lane];
        out[(size_t)n * 64 + lane] = (1.f - zg) * ng + zg * h;
    }
}

// ---------------------------------------------------------------------------
// Fully fused Set2Set: ALL 3 steps in one kernel (r11, validated).
__global__ __launch_bounds__(256) void lstm_all_kernel(
        const float* __restrict__ out, const int* __restrict__ off_b,
        float* __restrict__ e_ws,
        const float* __restrict__ wi, const float* __restrict__ wh,
        const float* __restrict__ bi, const float* __restrict__ bh,
        const float* __restrict__ hw1, const float* __restrict__ hb1,
        const float* __restrict__ hw2, const float* __restrict__ hb2,
        float* __restrict__ y) {
    int b = blockIdx.x;
    int t = threadIdx.x;
    __shared__ float qs[128], hs[64], cs[64], g[256];
    __shared__ float q[64];
    __shared__ float red[256], racc[256], sasum[4];

    if (t < 128) qs[t] = 0.f;
    if (t < 64) { hs[t] = 0.f; cs[t] = 0.f; }
    __syncthreads();

    int start = off_b[b], end = off_b[b + 1];

    for (int s = 0; s < 3; ++s) {
        // ---- LSTM cell ----
        {
            float acc = bi[t] + bh[t];
#pragma unroll 8
            for (int i = 0; i < 128; ++i) acc = fmaf(qs[i], wi[i * 256 + t], acc);
#pragma unroll 8
            for (int i = 0; i < 64; ++i) acc = fmaf(hs[i], wh[i * 256 + t], acc);
            g[t] = acc;
        }
        __syncthreads();
        if (t < 64) {
            float ig = 1.f / (1.f + expf(-g[t]));
            float fg = 1.f / (1.f + expf(-g[64 + t]));
            float gg = tanhf(g[128 + t]);
            float og = 1.f / (1.f + expf(-g[192 + t]));
            float c = fg * cs[t] + ig * gg;
            cs[t] = c;
            float h = og * tanhf(c);
            hs[t] = h;
            q[t] = h;
        }
        __syncthreads();

        // ---- attention ----
        float lmax = -1e30f;
        for (int n = start + t; n < end; n += 256) {
            float acc = 0.f;
#pragma unroll 16
            for (int d2 = 0; d2 < 64; ++d2) acc = fmaf(out[n * 64 + d2], q[d2], acc);
            e_ws[n] = acc;
            lmax = fmaxf(lmax, acc);
        }
        red[t] = lmax;
        __syncthreads();
        for (int s2 = 128; s2 > 0; s2 >>= 1) {
            if (t < s2) red[t] = fmaxf(red[t], red[t + s2]);
            __syncthreads();
        }
        float emax = red[0];
        int w = t >> 6, d = t & 63;
        float rl = 0.f, lasum = 0.f;
        for (int n = start + w; n < end; n += 4) {
            float a = expf(e_ws[n] - emax);
            rl = fmaf(a, out[n * 64 + d], rl);
            if (d == 0) lasum += a;
        }
        racc[t] = rl;
        if (d == 0) sasum[w] = lasum;
        __syncthreads();
        if (t < 64) {
            float r = racc[t] + racc[64 + t] + racc[128 + t] + racc[192 + t];
            float as = sasum[0] + sasum[1] + sasum[2] + sasum[3];
            as = fmaxf(as, 1e-16f);
            qs[t] = q[t];
            qs[64 + t] = r / as;
        }
        __syncthreads();
    }

    // ---- output head ----
    if (t < 64) {
        float acc = hb1[t];
#pragma unroll 8
        for (int i = 0; i < 128; ++i) acc = fmaf(qs[i], hw1[i * 64 + t], acc);
        acc = acc > 0.f ? acc : 0.f;
        float p = acc * hw2[t];
        for (int off = 32; off > 0; off >>= 1) p += __shfl_down(p, off, 64);
        if (t == 0) y[b] = p + hb2[0];
    }
}

extern "C" void kernel_launch(void* const* d_in, const int* in_sizes, int n_in,
                              void* d_out, int out_size, void* d_ws, size_t ws_size,
                              hipStream_t stream) {
    (void)in_sizes; (void)n_in; (void)out_size; (void)ws_size;
    const float* x        = (const float*)d_in[0];
    const float* ea       = (const float*)d_in[1];
    const int*   eidx     = (const int*)d_in[2];
    const int*   batch    = (const int*)d_in[3];
    const float* lin0_w   = (const float*)d_in[4];
    const float* lin0_b   = (const float*)d_in[5];
    const float* mlp_w1   = (const float*)d_in[6];
    const float* mlp_b1   = (const float*)d_in[7];
    const float* mlp_w2   = (const float*)d_in[8];
    const float* mlp_b2   = (const float*)d_in[9];
    const float* conv_root= (const float*)d_in[10];
    const float* conv_bias= (const float*)d_in[11];
    const float* gru_wi   = (const float*)d_in[12];
    const float* gru_wh   = (const float*)d_in[13];
    const float* gru_bi   = (const float*)d_in[14];
    const float* gru_bh   = (const float*)d_in[15];
    const float* lstm_wi  = (const float*)d_in[16];
    const float* lstm_wh  = (const float*)d_in[17];
    const float* lstm_bi  = (const float*)d_in[18];
    const float* lstm_bh  = (const float*)d_in[19];
    const float* lin1_w   = (const float*)d_in[20];
    const float* lin1_b   = (const float*)d_in[21];
    const float* lin2_w   = (const float*)d_in[22];
    const float* lin2_b   = (const float*)d_in[23];
    float* y = (float*)d_out;

    const int* src = eidx;
    const int* dst = eidx + E_;

    char* w = (char*)d_ws;
    auto carve = [&](size_t bytes) {
        char* p = w;
        w += (bytes + 255) & ~(size_t)255;
        return p;
    };
    float* out_buf = (float*)carve((size_t)N_ * DIM_ * 4);
    float* e_ws    = (float*)carve((size_t)N_ * 4);
    int*   off_b   = (int*)carve((size_t)(B_ + 1) * 4);
    _Float16* h1s  = (_Float16*)carve((size_t)E_ * MLP_H_ * 2);
    _Float16* Bf   = (_Float16*)carve((size_t)PC2_ * 64 * 2);
    int*   src_off = (int*)carve((size_t)(N_ + 1) * 4);
    int*   dsts    = (int*)carve((size_t)E_ * 4);
    // contiguous zero zone (single memset)
    char*  zero0   = w;
    float* agg     = (float*)carve((size_t)N_ * DIM_ * 4);
    float* cnt     = (float*)carve((size_t)N_ * 4);
    int*   cnt_src = (int*)carve((size_t)N_ * 4);
    int*   cur     = (int*)carve((size_t)N_ * 4);
    size_t zbytes  = (size_t)(w - zero0);

    hipMemsetAsync(zero0, 0, zbytes, stream);

    setup_a<<<LIN0_BLKS + DEG_BLKS + PREPB_BLKS, 256, 0, stream>>>(
        x, lin0_w, lin0_b, out_buf, src, dst, cnt, cnt_src, batch, off_b,
        mlp_w2, mlp_b2, Bf);
    scan_src<<<1, 256, 0, stream>>>(cnt_src, src_off);
    scatter_mlp1<<<(E_ + 255) / 256, 256, 0, stream>>>(src, dst, cur, src_off,
                                                       ea, mlp_w1, mlp_b1,
                                                       dsts, h1s);

    for (int step = 0; step < 3; ++step) {
        fused_msg<<<N_ / 16, 512, 0, stream>>>(out_buf, Bf, h1s, dsts,
                                               src_off, agg);
        gru_kernel<<<N_ / 32, 256, 0, stream>>>(out_buf, agg, cnt, conv_root,
                                                conv_bias, gru_wi, gru_wh,
                                                gru_bi, gru_bh);
    }

    lstm_all_kernel<<<B_, 256, 0, stream>>>(out_buf, off_b, e_ws,
                                            lstm_wi, lstm_wh, lstm_bi, lstm_bh,
                                            lin1_w, lin1_b, lin2_w, lin2_b, y);
}